// Round 6
// baseline (306.226 us; speedup 1.0000x reference)
//
#include <hip/hip_runtime.h>

#define N_NODES 50000
#define N_EDGES 800000
#define C_IN    128
#define C_HID   256
#define C_OUT   128
#define YSTRIDE 512       // bf16: [y_src 0..255 | y_dst 256..511]; after fused kernel,
                          // ch 256..415 of each row are overwritten with segb
                          // [z-mean 0..127 | attr 128 | zeros 129..159]

typedef __bf16 bf16x8 __attribute__((ext_vector_type(8)));
typedef float  f32x4  __attribute__((ext_vector_type(4)));

__device__ __forceinline__ unsigned short f2bf(float x) {
    unsigned u = __float_as_uint(x);
    u = (u + 0x7FFF + ((u >> 16) & 1)) >> 16;   // RNE
    return (unsigned short)u;
}

// ---------- fused prep: cast_z | hist(+epos capture) | bpack | wa1b | wa2b ----------
// The hist atomicAdd's return value IS the within-node slot index — capturing it
// into epos[] makes the later fill pass atomic-free.
__global__ __launch_bounds__(256) void prep_kernel(
    const float* __restrict__ z, const int* __restrict__ ei,
    const float* __restrict__ We1, const float* __restrict__ Wa1,
    const float* __restrict__ Wa2,
    unsigned short* __restrict__ zb, int* __restrict__ cnt, int* __restrict__ epos,
    unsigned short* __restrict__ Bpack, unsigned short* __restrict__ Wa1b,
    unsigned short* __restrict__ Wa2b)
{
    const int b = blockIdx.x;
    const int tid = threadIdx.x;
    if (b < 6250) {                                   // cast_z: 6250*256 = 1.6M float4
        int t = b * 256 + tid;
        float4 v = ((const float4*)z)[t];
        ushort4 o;
        o.x = f2bf(v.x); o.y = f2bf(v.y); o.z = f2bf(v.z); o.w = f2bf(v.w);
        ((ushort4*)zb)[t] = o;
    } else if (b < 6250 + 3125) {                     // hist: 3125*256 = 800000
        int e = (b - 6250) * 256 + tid;
        epos[e] = atomicAdd(&cnt[ei[N_EDGES + e]], 1);
    } else if (b < 6250 + 3125 + 32) {                // Bpack (We1 B-frags, 8ks x 16nt)
        int t = (b - 6250 - 3125) * 256 + tid;        // 8192 lane-slots
        int lane = t & 63, nt = (t >> 6) & 15, ks = t >> 10;
        int n  = nt * 16 + (lane & 15);
        int kb = ks * 32 + (lane >> 4) * 8;
        #pragma unroll
        for (int j = 0; j < 8; ++j)
            Bpack[t * 8 + j] = f2bf(We1[(kb + j) * C_HID + n]);
    } else if (b < 6250 + 3125 + 32 + 20) {           // Wa1b (node layer1)
        int t = (b - 6250 - 3125 - 32) * 256 + tid;
        if (t >= 5 * 16 * 64) return;
        int lane = t & 63, nt = (t >> 6) & 15, ks = t >> 10;
        int n = nt * 16 + (lane & 15);
        #pragma unroll
        for (int j = 0; j < 8; ++j) {
            int k = ks * 32 + (lane >> 4) * 8 + j;
            float v = 0.f;
            if (k < 128)       v = Wa1[(k + 1) * C_HID + n];
            else if (k == 128) v = Wa1[0 * C_HID + n];
            Wa1b[t * 8 + j] = f2bf(v);
        }
    } else {                                          // Wa2b (node layer2)
        int t = (b - 6250 - 3125 - 32 - 20) * 256 + tid;
        if (t >= 8 * 8 * 64) return;
        int lane = t & 63, nt = (t >> 6) & 7, ks = t >> 9;
        int n  = nt * 16 + (lane & 15);
        int kb = ks * 32 + (lane >> 4) * 8;
        #pragma unroll
        for (int j = 0; j < 8; ++j)
            Wa2b[t * 8 + j] = f2bf(Wa2[(kb + j) * C_OUT + n]);
    }
}

// ---------- CSR scan: 1024 threads, 49 ints/thread (1024*49 = 50176 exact) ----------
__global__ __launch_bounds__(1024) void scan_kernel(const int* __restrict__ cnt,
                                                    int* __restrict__ offsets) {
    const int tid = threadIdx.x;
    const int base = tid * 49;
    int c[49];
    int sum = 0;
    #pragma unroll
    for (int i = 0; i < 49; ++i) { c[i] = cnt[base + i]; sum += c[i]; }
    const int lane = tid & 63, w = tid >> 6;          // 16 waves
    int v = sum;
    #pragma unroll
    for (int off = 1; off < 64; off <<= 1) {
        int t = __shfl_up(v, off, 64);
        if (lane >= off) v += t;
    }
    __shared__ int s_w[16];
    if (lane == 63) s_w[w] = v;
    __syncthreads();
    int wbase = 0;
    #pragma unroll
    for (int i = 0; i < 16; ++i) wbase += (i < w) ? s_w[i] : 0;
    int run = wbase + v - sum;
    #pragma unroll
    for (int i = 0; i < 49; ++i) { offsets[base + i] = run; run += c[i]; }
}

// ---------- merged Y GEMM + fill (ygemm blocks FIRST) ----------
__global__ __launch_bounds__(256, 2) void fy_kernel(
    const int* __restrict__ ei, const float* __restrict__ eattr,
    const int* __restrict__ offsets, const int* __restrict__ epos,
    int4* __restrict__ erec,
    const unsigned short* __restrict__ zb, const unsigned short* __restrict__ Bpack,
    const float* __restrict__ be1, unsigned short* __restrict__ Y)
{
    const int tid = threadIdx.x;
    if (blockIdx.x >= 1564) {                         // ---- fill (atomic-free) ----
        int e = (blockIdx.x - 1564) * 256 + tid;      // 3125*256 = 800000 exact
        int d = ei[N_EDGES + e];
        erec[offsets[d] + epos[e]] = make_int4(ei[e], e, __float_as_int(eattr[e]), 0);
        return;
    }
    // ---- ygemm ----
    __shared__ __align__(16) unsigned short s_a[64][136];
    const int yb = blockIdx.x;                        // 0..1563
    const int n0 = (yb >> 1) * 64;
    const int half = yb & 1;
    const int lane = tid & 63, w = tid >> 6;
    const int m16 = lane & 15, quad = lane >> 4;

    #pragma unroll
    for (int i = 0; i < 4; ++i) {
        int c = tid + i * 256;
        int row = c >> 4, col = (c & 15) * 8;
        *(uint4*)&s_a[row][col] = *(const uint4*)(zb + (size_t)(n0 + row) * C_IN + col);
    }

    bf16x8 bfr[4][4];
    {
        const bf16x8* bp = (const bf16x8*)Bpack;
        #pragma unroll
        for (int ks = 0; ks < 4; ++ks)
            #pragma unroll
            for (int nt = 0; nt < 4; ++nt)
                bfr[ks][nt] = bp[((half * 4 + ks) * 16 + (w * 4 + nt)) * 64 + lane];
    }
    __syncthreads();

    f32x4 acc[4][4];
    #pragma unroll
    for (int mt = 0; mt < 4; ++mt)
        #pragma unroll
        for (int nt = 0; nt < 4; ++nt)
            acc[mt][nt] = (f32x4){0.f, 0.f, 0.f, 0.f};

    #pragma unroll
    for (int ks = 0; ks < 4; ++ks) {
        #pragma unroll
        for (int mt = 0; mt < 4; ++mt) {
            bf16x8 a = *(const bf16x8*)&s_a[mt * 16 + m16][ks * 32 + quad * 8];
            #pragma unroll
            for (int nt = 0; nt < 4; ++nt)
                acc[mt][nt] = __builtin_amdgcn_mfma_f32_16x16x32_bf16(
                    a, bfr[ks][nt], acc[mt][nt], 0, 0, 0);
        }
    }

    #pragma unroll
    for (int nt = 0; nt < 4; ++nt) {
        const int c = w * 64 + nt * 16 + m16;           // col within half
        const float b = half ? be1[c] : 0.f;
        #pragma unroll
        for (int mt = 0; mt < 4; ++mt)
            #pragma unroll
            for (int r = 0; r < 4; ++r) {
                const int node = n0 + mt * 16 + quad * 4 + r;
                Y[(size_t)node * YSTRIDE + half * 256 + c] = f2bf(acc[mt][nt][r] + b);
            }
    }
}

// ---------- fused edge elementwise + gather-mean (ONE WAVE per dst node) ----------
// 3-stage software pipeline: records are TWO groups ahead (f in flight), the
// z/Y gathers ONE group ahead. In steady state every wait is on a load issued
// a full iteration earlier — no same-iteration dependent waits (R3's mistake
// was issuing records and immediately waiting on them to issue gathers).
// Record scalars (attr, edge_id) are consumed at iteration start so record
// registers rotate without extending liveness. WG=64 (R2-proven).
__device__ __forceinline__ float dot8(uint4 q, const float* __restrict__ d,
                                      const float* __restrict__ wv, float p) {
    const unsigned u[4] = {q.x, q.y, q.z, q.w};
    #pragma unroll
    for (int j = 0; j < 4; ++j) {
        const float lo = __uint_as_float(u[j] << 16)         + d[2 * j];
        const float hi = __uint_as_float(u[j] & 0xffff0000u) + d[2 * j + 1];
        p = fmaf(fmaxf(lo, 0.f), wv[2 * j],     p);
        p = fmaf(fmaxf(hi, 0.f), wv[2 * j + 1], p);
    }
    return p;
}

__global__ __launch_bounds__(64, 5) void fused_eg_kernel(
    unsigned short* __restrict__ Y, const unsigned short* __restrict__ zb,
    const int* __restrict__ offsets, const int4* __restrict__ erec,
    const float* __restrict__ We2, const float* __restrict__ be2,
    float* __restrict__ edge_out)
{
    const int lane = threadIdx.x;
    const int n = blockIdx.x;
    const int c = lane & 15, g = lane >> 4;           // 16 lanes per edge-slot
    const int beg = offsets[n], end = offsets[n + 1], deg = end - beg;
    const float be2v = be2[0];

    // hoist dst half-row (ch c*8+0..7 and 128+c*8+0..7) + matching We2
    float d0[8], d1[8], w0[8], w1[8];
    {
        const unsigned short* yh = Y + (size_t)n * YSTRIDE + 256;
        uint4 q0 = *(const uint4*)(yh + c * 8);
        uint4 q1 = *(const uint4*)(yh + 128 + c * 8);
        const unsigned a0[4] = {q0.x, q0.y, q0.z, q0.w};
        const unsigned a1[4] = {q1.x, q1.y, q1.z, q1.w};
        #pragma unroll
        for (int j = 0; j < 4; ++j) {
            d0[2 * j]     = __uint_as_float(a0[j] << 16);
            d0[2 * j + 1] = __uint_as_float(a0[j] & 0xffff0000u);
            d1[2 * j]     = __uint_as_float(a1[j] << 16);
            d1[2 * j + 1] = __uint_as_float(a1[j] & 0xffff0000u);
        }
        #pragma unroll
        for (int j = 0; j < 8; ++j) {
            w0[j] = We2[c * 8 + j];
            w1[j] = We2[128 + c * 8 + j];
        }
    }

    float ax = 0.f, ay = 0.f;                  // lane owns z-channels lane*2, lane*2+1
    float asum = 0.f;                          // uniform across wave
    const int nfull = deg >> 2;
    int i = beg;

    int4 r0, r1, r2, r3;                       // records of CURRENT group (resident)
    int4 f0, f1, f2, f3;                       // records of NEXT group (in flight)
    unsigned zu0, zu1, zu2, zu3;               // z gathers of current group
    uint4 yq0, yq1;                            // Y gathers of current group

    if (nfull) {                               // prologue: one exposed latency, once
        r0 = erec[i]; r1 = erec[i + 1]; r2 = erec[i + 2]; r3 = erec[i + 3];
        zu0 = *(const unsigned*)(zb + (size_t)r0.x * C_IN + lane * 2);
        zu1 = *(const unsigned*)(zb + (size_t)r1.x * C_IN + lane * 2);
        zu2 = *(const unsigned*)(zb + (size_t)r2.x * C_IN + lane * 2);
        zu3 = *(const unsigned*)(zb + (size_t)r3.x * C_IN + lane * 2);
        const int sg = (g == 0) ? r0.x : (g == 1) ? r1.x : (g == 2) ? r2.x : r3.x;
        const unsigned short* yr = Y + (size_t)sg * YSTRIDE;
        yq0 = *(const uint4*)(yr + c * 8);
        yq1 = *(const uint4*)(yr + 128 + c * 8);
        if (nfull > 1) {
            f0 = erec[i + 4]; f1 = erec[i + 5]; f2 = erec[i + 6]; f3 = erec[i + 7];
        }
    }

    for (int it = 0; it < nfull; ++it) {
        // consume current records' scalars (frees r for rotation)
        asum += __int_as_float(r0.z) + __int_as_float(r1.z)
              + __int_as_float(r2.z) + __int_as_float(r3.z);
        const int eg = (g == 0) ? r0.y : (g == 1) ? r1.y : (g == 2) ? r2.y : r3.y;
        i += 4;

        unsigned nz0 = 0, nz1 = 0, nz2 = 0, nz3 = 0;
        uint4 nyq0 = {0, 0, 0, 0}, nyq1 = {0, 0, 0, 0};
        if (it + 1 < nfull) {
            const int4 t0 = f0, t1 = f1, t2 = f2, t3 = f3;   // waits f: issued 1 iter ago
            if (it + 2 < nfull) {                            // records 2 ahead, in flight
                f0 = erec[i + 4]; f1 = erec[i + 5];
                f2 = erec[i + 6]; f3 = erec[i + 7];
            }
            // issue gathers for group it+1 (consumed next iteration)
            nz0 = *(const unsigned*)(zb + (size_t)t0.x * C_IN + lane * 2);
            nz1 = *(const unsigned*)(zb + (size_t)t1.x * C_IN + lane * 2);
            nz2 = *(const unsigned*)(zb + (size_t)t2.x * C_IN + lane * 2);
            nz3 = *(const unsigned*)(zb + (size_t)t3.x * C_IN + lane * 2);
            const int sg = (g == 0) ? t0.x : (g == 1) ? t1.x : (g == 2) ? t2.x : t3.x;
            const unsigned short* yr = Y + (size_t)sg * YSTRIDE;
            nyq0 = *(const uint4*)(yr + c * 8);
            nyq1 = *(const uint4*)(yr + 128 + c * 8);
            r0 = t0; r1 = t1; r2 = t2; r3 = t3;
        }
        // ---- compute on current gathers (issued one full iteration ago) ----
        ax += __uint_as_float(zu0 << 16) + __uint_as_float(zu1 << 16)
            + __uint_as_float(zu2 << 16) + __uint_as_float(zu3 << 16);
        ay += __uint_as_float(zu0 & 0xffff0000u) + __uint_as_float(zu1 & 0xffff0000u)
            + __uint_as_float(zu2 & 0xffff0000u) + __uint_as_float(zu3 & 0xffff0000u);
        float p = dot8(yq0, d0, w0, 0.f);
        p = dot8(yq1, d1, w1, p);
        p += __shfl_xor(p, 1, 64);
        p += __shfl_xor(p, 2, 64);
        p += __shfl_xor(p, 4, 64);
        p += __shfl_xor(p, 8, 64);
        if (c == 0) edge_out[eg] = p + be2v;
        // rotate gather buffers
        zu0 = nz0; zu1 = nz1; zu2 = nz2; zu3 = nz3;
        yq0 = nyq0; yq1 = nyq1;
    }
    for (; i < end; ++i) {                     // tail (<=3 edges)
        const int4 r = erec[i];
        asum += __int_as_float(r.z);
        const unsigned u = *(const unsigned*)(zb + (size_t)r.x * C_IN + lane * 2);
        ax += __uint_as_float(u << 16);
        ay += __uint_as_float(u & 0xffff0000u);
        const unsigned short* yr = Y + (size_t)r.x * YSTRIDE;
        const uint4 q0 = *(const uint4*)(yr + c * 8);
        const uint4 q1 = *(const uint4*)(yr + 128 + c * 8);
        float p = dot8(q0, d0, w0, 0.f);
        p = dot8(q1, d1, w1, p);
        p += __shfl_xor(p, 1, 64);
        p += __shfl_xor(p, 2, 64);
        p += __shfl_xor(p, 4, 64);
        p += __shfl_xor(p, 8, 64);
        if (lane == 0) edge_out[r.y] = p + be2v;
    }

    const float inv = (deg > 0) ? 1.0f / (float)deg : 0.0f;
    unsigned short* segn = Y + (size_t)n * YSTRIDE + 256;   // in-place: Y_hi is dead now
    ushort2 o; o.x = f2bf(ax * inv); o.y = f2bf(ay * inv);
    *(ushort2*)(segn + lane * 2) = o;
    if (lane < 16) {
        ushort2 pz; pz.x = (lane == 0) ? f2bf(asum * inv) : (unsigned short)0; pz.y = 0;
        *(ushort2*)(segn + 128 + lane * 2) = pz;   // attr @128, zeros 129..159
    }
}

// ---------- node MLP: bf16 MFMA, both layers, h via LDS round-trip ----------
// segb lives in Y ch 256..415 of each row (stride YSTRIDE).
__global__ __launch_bounds__(256, 2) void node_mfma_kernel(
    const unsigned short* __restrict__ segb, const unsigned short* __restrict__ Wa1b,
    const float* __restrict__ ba1, const unsigned short* __restrict__ Wa2b,
    const float* __restrict__ ba2, float* __restrict__ x_out)
{
    __shared__ __align__(16) unsigned short s_a[64][168];
    __shared__ __align__(16) unsigned short s_h[64][264];
    const int tid  = threadIdx.x;
    const int lane = tid & 63, w = tid >> 6;
    const int m16 = lane & 15, quad = lane >> 4;
    const int n0 = blockIdx.x * 64;

    {
        const unsigned short* src = segb + (size_t)n0 * YSTRIDE + 256;
        #pragma unroll
        for (int i = 0; i < 5; ++i) {
            int c = tid + i * 256;
            int row = c / 20, col = c - row * 20;
            *(uint4*)&s_a[row][col * 8] =
                *(const uint4*)(src + (size_t)row * YSTRIDE + col * 8);
        }
    }

    bf16x8 bfr1[5][4];
    {
        const bf16x8* bp = (const bf16x8*)Wa1b;
        #pragma unroll
        for (int ks = 0; ks < 5; ++ks)
            #pragma unroll
            for (int nt = 0; nt < 4; ++nt)
                bfr1[ks][nt] = bp[(ks * 16 + (w * 4 + nt)) * 64 + lane];
    }
    __syncthreads();

    f32x4 acc1[4][4];
    #pragma unroll
    for (int mt = 0; mt < 4; ++mt)
        #pragma unroll
        for (int nt = 0; nt < 4; ++nt)
            acc1[mt][nt] = (f32x4){0.f, 0.f, 0.f, 0.f};

    #pragma unroll
    for (int ks = 0; ks < 5; ++ks) {
        #pragma unroll
        for (int mt = 0; mt < 4; ++mt) {
            bf16x8 a = *(const bf16x8*)&s_a[mt * 16 + m16][ks * 32 + quad * 8];
            #pragma unroll
            for (int nt = 0; nt < 4; ++nt)
                acc1[mt][nt] = __builtin_amdgcn_mfma_f32_16x16x32_bf16(
                    a, bfr1[ks][nt], acc1[mt][nt], 0, 0, 0);
        }
    }

    #pragma unroll
    for (int nt = 0; nt < 4; ++nt) {
        const int chan = w * 64 + nt * 16 + m16;
        const float b1 = ba1[chan];
        #pragma unroll
        for (int mt = 0; mt < 4; ++mt)
            #pragma unroll
            for (int r = 0; r < 4; ++r) {
                const int node = mt * 16 + quad * 4 + r;
                s_h[node][chan] = f2bf(fmaxf(acc1[mt][nt][r] + b1, 0.f));
            }
    }

    bf16x8 bfr2[8][2];
    {
        const bf16x8* bp = (const bf16x8*)Wa2b;
        #pragma unroll
        for (int ks = 0; ks < 8; ++ks)
            #pragma unroll
            for (int nt = 0; nt < 2; ++nt)
                bfr2[ks][nt] = bp[(ks * 8 + (w * 2 + nt)) * 64 + lane];
    }
    __syncthreads();

    f32x4 acc2[4][2];
    #pragma unroll
    for (int mt = 0; mt < 4; ++mt)
        #pragma unroll
        for (int nt = 0; nt < 2; ++nt)
            acc2[mt][nt] = (f32x4){0.f, 0.f, 0.f, 0.f};

    #pragma unroll
    for (int ks = 0; ks < 8; ++ks) {
        #pragma unroll
        for (int mt = 0; mt < 4; ++mt) {
            bf16x8 a = *(const bf16x8*)&s_h[mt * 16 + m16][ks * 32 + quad * 8];
            #pragma unroll
            for (int nt = 0; nt < 2; ++nt)
                acc2[mt][nt] = __builtin_amdgcn_mfma_f32_16x16x32_bf16(
                    a, bfr2[ks][nt], acc2[mt][nt], 0, 0, 0);
        }
    }

    #pragma unroll
    for (int nt = 0; nt < 2; ++nt) {
        const int j = w * 32 + nt * 16 + m16;
        const float b2 = ba2[j];
        #pragma unroll
        for (int mt = 0; mt < 4; ++mt)
            #pragma unroll
            for (int r = 0; r < 4; ++r) {
                const int node = n0 + mt * 16 + quad * 4 + r;
                if (node < N_NODES)
                    x_out[(size_t)node * C_OUT + j] = acc2[mt][nt][r] + b2;
            }
    }
}

// ---------- launch ----------
// ws layout (bytes), total ~81.1 MB:
//   Y         51,249,152   (50048 x 512 bf16; ch 256..415 become segb in-place)
//   zb        12,812,288   (50048 rows; 50000 valid, tail garbage never used)
//   Bpack        131,072
//   Wa1b          81,920
//   Wa2b          65,536
//   cnt          200,704   (50176 ints, zero-padded for scan)
//   offsets      200,704   (padded to 50176 ints for scan)
//   epos       3,200,000   (per-edge within-node slot, captured from hist atomic)
//   erec      12,800,000   (800000 x int4 {src, edge_id, attr_bits, 0})

extern "C" void kernel_launch(void* const* d_in, const int* in_sizes, int n_in,
                              void* d_out, int out_size, void* d_ws, size_t ws_size,
                              hipStream_t stream) {
    const float* z     = (const float*)d_in[0];
    const int*   ei    = (const int*)d_in[1];     // int32 per harness contract
    const float* eattr = (const float*)d_in[2];
    const float* Wa1   = (const float*)d_in[3];
    const float* ba1   = (const float*)d_in[4];
    const float* Wa2   = (const float*)d_in[5];
    const float* ba2   = (const float*)d_in[6];
    const float* We1   = (const float*)d_in[7];
    const float* be1   = (const float*)d_in[8];
    const float* We2   = (const float*)d_in[9];
    const float* be2   = (const float*)d_in[10];

    float* x_out    = (float*)d_out;
    float* edge_out = x_out + (size_t)N_NODES * C_OUT;

    char* wsb = (char*)d_ws;
    size_t off = 0;
    unsigned short* Y        = (unsigned short*)(wsb + off); off += 51249152;
    unsigned short* zb       = (unsigned short*)(wsb + off); off += 12812288;
    unsigned short* Bpack    = (unsigned short*)(wsb + off); off += 131072;
    unsigned short* Wa1b     = (unsigned short*)(wsb + off); off += 81920;
    unsigned short* Wa2b     = (unsigned short*)(wsb + off); off += 65536;
    int*            cnt      = (int*)(wsb + off);            off += 200704;
    int*            offsets  = (int*)(wsb + off);            off += 200704;
    int*            epos     = (int*)(wsb + off);            off += 3200000;
    int4*           erec     = (int4*)(wsb + off);           off += 12800000;

    hipMemsetAsync(cnt, 0, 200704, stream);

    prep_kernel<<<6250 + 3125 + 32 + 20 + 16, 256, 0, stream>>>(
        z, ei, We1, Wa1, Wa2, zb, cnt, epos, Bpack, Wa1b, Wa2b);

    scan_kernel<<<1, 1024, 0, stream>>>(cnt, offsets);

    fy_kernel<<<1564 + 3125, 256, 0, stream>>>(ei, eattr, offsets, epos, erec,
                                               zb, Bpack, be1, Y);

    fused_eg_kernel<<<N_NODES, 64, 0, stream>>>(
        Y, zb, offsets, erec, We2, be2, edge_out);

    node_mfma_kernel<<<(N_NODES + 63) / 64, 256, 0, stream>>>(Y, Wa1b, ba1, Wa2b,
                                                              ba2, x_out);
}